// Round 12
// baseline (3389.379 us; speedup 1.0000x reference)
//
#include <hip/hip_runtime.h>
#include <math.h>

// Problem constants (B=256, T=784, H=512, C=10)
#define TSTEPS 784
#define BATCH  256
#define HID    512
#define NCLS   10

// 64 groups x 8 member-blocks, 2 blocks/CU (independent groups co-resident
// per CU -> poll/barrier of one block hides under compute of the other).
// Member m holds W[:, m*64..m*64+64) in REGISTERS; each group owns 4 batch
// rows. h exchange: tagged 8B pairs (tag=step | f32 value) via relaxed
// agent-scope atomics. Wave wv polls ONLY slice wv (its own k-chunk);
// member m's own slice passes through LDS (wave m never polls MALL).
//
// Overwrite safety: member M stores slice@t+2 over slice@t only after M's
// B1 at t+2, which requires all M's waves validated h_{t+1}; producer S
// stored h_{t+1} only after S's B1 at t+1, which required S's wave-M
// validating slice M@t. So all consumers finished reading slice@t before
// it is overwritten.
//
// Co-residency: 512 blocks, LDS 76KB/block -> exactly 2 blocks/CU
// (2x76<=160<3x76), VGPR ~100 <= 128 -> 4 waves/SIMD. All 512 resident.
#define NBLK   512
#define NGRP   64
#define MEMB   8
#define BPG    4     // batch rows per group
#define JS     64    // output columns per block
#define NTHR   512

#define SMEM_BYTES (76*1024)

__device__ __forceinline__ float fast_tanh(float x) {
    // tanh(x) = sign(x)*(1 - 2/(e^{2|x|}+1)); exp overflow -> inf -> +-1. Safe.
    float ax = fabsf(x);
    float e  = __expf(2.0f * ax);
    float r  = 1.0f - 2.0f / (e + 1.0f);
    return copysignf(r, x);
}

__device__ __forceinline__ unsigned long long coh_load64(const unsigned long long* p) {
    return __hip_atomic_load(p, __ATOMIC_RELAXED, __HIP_MEMORY_SCOPE_AGENT);
}
__device__ __forceinline__ void coh_store64(unsigned long long* p, unsigned long long v) {
    __hip_atomic_store(p, v, __ATOMIC_RELAXED, __HIP_MEMORY_SCOPE_AGENT);
}

// Tail-only: stage full group h [BPG][512] into dst[b*HID+k].
__device__ __forceinline__ void stage_group_h(const unsigned long long* src,
                                              unsigned int exp_tag, float* dst,
                                              int tid)
{
    unsigned long long v[BPG];
    unsigned int ok = 0;
    const unsigned int all = (1u << BPG) - 1u;
    while (ok != all) {
        #pragma unroll
        for (int q = 0; q < BPG; ++q)
            if (!(ok & (1u << q))) v[q] = coh_load64(src + tid + q*NTHR);
        #pragma unroll
        for (int q = 0; q < BPG; ++q)
            if (!(ok & (1u << q)) && (unsigned int)(v[q] >> 32) == exp_tag)
                ok |= 1u << q;
    }
    #pragma unroll
    for (int q = 0; q < BPG; ++q)
        dst[tid + q*NTHR] = __uint_as_float((unsigned int)v[q]);
}

__global__ void __launch_bounds__(NTHR, 4)
rnn_kernel(const float* __restrict__ inputs, const int* __restrict__ y,
           const int* __restrict__ order,  const float* __restrict__ U,
           const float* __restrict__ W,    const float* __restrict__ bias,
           const float* __restrict__ lin_w, const float* __restrict__ lin_b,
           unsigned long long* __restrict__ pairs, // [2][BATCH][HID] (tag,val)
           float* __restrict__ gloss, float* __restrict__ gcorr)
{
    extern __shared__ float smem[];
    float* hl   = smem;          // [wave][b<4][64]: staged h, region wv = slice wv (8 KB)
    float* part = smem + 2048;   // [wave][b<4][64] partials; tail reuses as [4][512] (8 KB)

    const int tid = threadIdx.x;
    const int bid = blockIdx.x;
    const int m   = bid >> 6;     // member 0..7  (column slice)
    const int g   = bid & 63;     // group 0..63
    const int jbase = m * JS;
    const int grow  = g * BPG;    // first global batch row of this group

    // k-loop mapping: wave wv covers k in [wv*64, wv*64+64); lane -> (jq, ks)
    const int wv = tid >> 6;
    const int ln = tid & 63;
    const int jq = ln & 15;
    const int ks = ln >> 4;
    const int kbase = wv*64 + ks*16;
    const int hbase = wv*256 + ks*16;     // LDS base of this thread's k-subrange (4 rows x 64)

    // ---- one-time: this thread's W tile (16 k-rows x 4 cols) into registers ----
    float4 wreg[16];
    #pragma unroll
    for (int r = 0; r < 16; ++r)
        wreg[r] = *(const float4*)&W[(size_t)(kbase + r)*HID + jbase + jq*4];

    // output mapping: waves 0..3 = batch rows, lane = column; waves 4..7 idle in phase 5/6
    const int rb = wv;            // row (valid when wv < BPG)
    const int rj = ln;
    const float Ureg = U[jbase + rj];
    const float Breg = bias[jbase + rj];
    const float* xrow = inputs + (size_t)(grow + (rb & 3)) * TSTEPS;
    unsigned long long* pout = pairs + (size_t)(grow + (rb & 3))*HID + jbase + rj; // + buf*BATCH*HID
    // poll source for wave wv: slice wv of the group's rows
    const unsigned long long* psrc = pairs + (size_t)grow*HID + wv*64 + ln;  // + buf*BATCH*HID + b*HID

    for (int t = 0; t < TSTEPS; ++t) {
        const int pix = order[t];
        const float xv = xrow[pix];      // issued early, used at the end
        float sum;
        if (t == 0) {
            sum = 0.0f;                  // h0 = 0
        } else {
            // ---- phase 1: per-wave poll of slice wv (skip own slice: in LDS) ----
            if (wv != m) {
                const unsigned long long* src = psrc + (size_t)((t-1) & 1)*BATCH*HID;
                const unsigned int etag = (unsigned int)(t - 1);
                unsigned long long v[BPG];
                unsigned int ok = 0;
                while (ok != 0xFu) {
                    #pragma unroll
                    for (int b = 0; b < BPG; ++b)
                        if (!(ok & (1u << b))) v[b] = coh_load64(src + (size_t)b*HID);
                    #pragma unroll
                    for (int b = 0; b < BPG; ++b)
                        if (!(ok & (1u << b)) && (unsigned int)(v[b] >> 32) == etag)
                            ok |= 1u << b;
                }
                #pragma unroll
                for (int b = 0; b < BPG; ++b)
                    hl[wv*256 + b*64 + ln] = __uint_as_float((unsigned int)v[b]);
            }
            // no barrier: each wave reads only its own hl region (wave m's was
            // written by rows-waves before last step's B2).

            // ---- phase 2: k-loop partials over this wave's k-chunk ----
            float acc[BPG][4];
            #pragma unroll
            for (int b = 0; b < BPG; ++b) { acc[b][0]=0.f; acc[b][1]=0.f; acc[b][2]=0.f; acc[b][3]=0.f; }

            #pragma unroll
            for (int kk = 0; kk < 16; kk += 4) {
                const float4 w0 = wreg[kk+0];
                const float4 w1 = wreg[kk+1];
                const float4 w2 = wreg[kk+2];
                const float4 w3 = wreg[kk+3];
                #pragma unroll
                for (int b = 0; b < BPG; ++b) {
                    float4 hv = *(float4*)&hl[hbase + b*64 + kk];   // 16-lane broadcast
                    acc[b][0] = fmaf(hv.w,w3.x, fmaf(hv.z,w2.x, fmaf(hv.y,w1.x, fmaf(hv.x,w0.x, acc[b][0]))));
                    acc[b][1] = fmaf(hv.w,w3.y, fmaf(hv.z,w2.y, fmaf(hv.y,w1.y, fmaf(hv.x,w0.y, acc[b][1]))));
                    acc[b][2] = fmaf(hv.w,w3.z, fmaf(hv.z,w2.z, fmaf(hv.y,w1.z, fmaf(hv.x,w0.z, acc[b][2]))));
                    acc[b][3] = fmaf(hv.w,w3.w, fmaf(hv.z,w2.w, fmaf(hv.y,w1.w, fmaf(hv.x,w0.w, acc[b][3]))));
                }
            }

            // ---- phase 3: reduce over ks within wave, write partials ----
            #pragma unroll
            for (int b = 0; b < BPG; ++b) {
                #pragma unroll
                for (int jj = 0; jj < 4; ++jj) {
                    float v = acc[b][jj];
                    v += __shfl_xor(v, 16, 64);
                    v += __shfl_xor(v, 32, 64);
                    acc[b][jj] = v;
                }
            }
            if (ks == 0) {
                #pragma unroll
                for (int b = 0; b < BPG; ++b)
                    *(float4*)&part[wv*256 + b*64 + jq*4] =
                        make_float4(acc[b][0], acc[b][1], acc[b][2], acc[b][3]);
            }
            __syncthreads();   // B1: partials ready

            // ---- phase 5: cross-wave sum (waves 0..3 only) ----
            sum = 0.0f;
            #pragma unroll
            for (int w = 0; w < 8; ++w) sum += part[w*256 + (rb & 3)*64 + rj];
        }

        // ---- phase 6: activation, own-slice LDS pass, MALL store (waves 0..3) ----
        if (wv < BPG) {
            const float pre  = fmaf(xv, Ureg, sum + Breg);
            const float hval = fast_tanh(pre);
            hl[m*256 + rb*64 + rj] = hval;   // own slice -> wave m's region (next step)
            const unsigned long long pv =
                ((unsigned long long)(unsigned int)t << 32) | __float_as_uint(hval);
            coh_store64(pout + (size_t)(t & 1)*BATCH*HID, pv);   // fire-and-forget
        }
        __syncthreads();   // B2: hl[m] complete before next step's reads; also
                           // separates part reads (phase 5) from next B1 writes
    }

    // ---- tail: member 0 of each group computes logits / loss / correct ----
    if (m == 0) {
        const int fbuf = (TSTEPS - 1) & 1;
        const unsigned long long* gsrc = pairs + (size_t)grow*HID;
        stage_group_h(gsrc + (size_t)fbuf*BATCH*HID, (unsigned int)(TSTEPS - 1), part, tid);
        __syncthreads();

        __shared__ float lg[BPG][NCLS];
        __shared__ float sl[BPG], sc[BPG];
        if (tid < BPG*NCLS) {
            int b = tid / NCLS, c = tid - b*NCLS;
            float s = lin_b[c];
            for (int k = 0; k < HID; ++k)
                s = fmaf(part[b*HID + k], lin_w[k*NCLS + c], s);
            lg[b][c] = s;
        }
        __syncthreads();
        if (tid < BPG) {
            int b = tid;
            float mx = lg[b][0]; int bi = 0;
            #pragma unroll
            for (int c = 1; c < NCLS; ++c) if (lg[b][c] > mx) { mx = lg[b][c]; bi = c; }
            float se = 0.f;
            #pragma unroll
            for (int c = 0; c < NCLS; ++c) se += __expf(lg[b][c] - mx);
            float lse = mx + __logf(se);
            int yy = y[grow + b];
            sl[b] = lse - lg[b][yy];              // -log p(y)
            sc[b] = (bi == yy) ? 1.0f : 0.0f;
        }
        __syncthreads();
        if (tid == 0) {
            float L = 0.f, C = 0.f;
            for (int b = 0; b < BPG; ++b) { L += sl[b]; C += sc[b]; }
            gloss[g] = L; gcorr[g] = C;
        }
    }
}

__global__ void final_kernel(const float* gloss, const float* gcorr, float* out) {
    float L = 0.f, C = 0.f;
    for (int g = 0; g < NGRP; ++g) { L += gloss[g]; C += gcorr[g]; }
    out[0] = L / (float)BATCH;   // loss = mean(lse - logit_y)
    out[1] = C;                  // correct count
}

extern "C" void kernel_launch(void* const* d_in, const int* in_sizes, int n_in,
                              void* d_out, int out_size, void* d_ws, size_t ws_size,
                              hipStream_t stream)
{
    (void)in_sizes; (void)n_in; (void)out_size; (void)ws_size;
    const float* inputs = (const float*)d_in[0];
    const int*   y      = (const int*)  d_in[1];
    const int*   order  = (const int*)  d_in[2];
    const float* U      = (const float*)d_in[3];
    const float* W      = (const float*)d_in[4];
    const float* bias   = (const float*)d_in[5];
    const float* lin_w  = (const float*)d_in[6];
    const float* lin_b  = (const float*)d_in[7];
    float* out = (float*)d_out;

    char* ws = (char*)d_ws;
    unsigned long long* pairs = (unsigned long long*)ws;        // 2*256*512*8 = 2 MB
    float* gloss = (float*)(ws + 2*(size_t)BATCH*HID*8);
    float* gcorr = gloss + NGRP;
    // ws re-poisoned to 0xAA before every launch -> pair tags start at
    // 0xAAAAAAAA, never equal to a step tag (0..783). No init needed.

    (void)hipFuncSetAttribute((const void*)rnn_kernel,
                              hipFuncAttributeMaxDynamicSharedMemorySize, SMEM_BYTES);

    rnn_kernel<<<NBLK, NTHR, SMEM_BYTES, stream>>>(inputs, y, order, U, W, bias,
                                                   lin_w, lin_b, pairs, gloss, gcorr);
    final_kernel<<<1, 1, 0, stream>>>(gloss, gcorr, out);
}